// Round 1
// baseline (5119.810 us; speedup 1.0000x reference)
//
#include <hip/hip_runtime.h>

#define T_TOT 1024
#define BB 64
#define DD 128
#define HH 256
#define GG 1024
#define OO 64
#define LN_EPS 1e-3f

typedef unsigned int u32;
typedef _Float16 h2 __attribute__((ext_vector_type(2)));

__device__ __forceinline__ float fdot2(u32 a, u32 b, float c) {
  return __builtin_amdgcn_fdot2(__builtin_bit_cast(h2, a), __builtin_bit_cast(h2, b), c, false);
}
__device__ __forceinline__ u32 pkf16(float lo, float hi) {
  h2 v = { (_Float16)lo, (_Float16)hi };
  return __builtin_bit_cast(u32, v);
}
__device__ __forceinline__ float fast_sigmoid(float x) { return 1.0f / (1.0f + __expf(-x)); }
__device__ __forceinline__ float fast_tanh(float x) { return 2.0f / (1.0f + __expf(-2.0f * x)) - 1.0f; }

// ---------------- prep: pack Wh (4H x H) into f16 pairs, chunked by 8 along H ----
// whp4[kb*1024 + g] = 8 f16 = Wh[g][8kb .. 8kb+7]
__global__ void prep_wh(const float* __restrict__ Wh, uint4* __restrict__ whp4) {
  int id = blockIdx.x * 256 + threadIdx.x;     // 32768
  int kb = id >> 10, g = id & 1023;
  const float* p = Wh + (size_t)g * HH + kb * 8;
  uint4 o;
  o.x = pkf16(p[0], p[1]); o.y = pkf16(p[2], p[3]);
  o.z = pkf16(p[4], p[5]); o.w = pkf16(p[6], p[7]);
  whp4[id] = o;
}

// wip4[kp4*1024 + g] = 8 f16 = Wi[g][8*kp4 .. +7]
__global__ void prep_wi(const float* __restrict__ Wi, uint4* __restrict__ wip4) {
  int id = blockIdx.x * 256 + threadIdx.x;     // 16384
  int kp4 = id >> 10, g = id & 1023;
  const float* p = Wi + (size_t)g * DD + kp4 * 8;
  uint4 o;
  o.x = pkf16(p[0], p[1]); o.y = pkf16(p[2], p[3]);
  o.z = pkf16(p[4], p[5]); o.w = pkf16(p[6], p[7]);
  wip4[id] = o;
}

// ---------------- xproj GEMM: xph[ml][g] = sum_d x[b][t][d]*Wi[g][d] + bi[g]+bh[g]
// ml = tl*64 + b (chunk-local), block: 16 m-rows x 256 g; grid (nm/16, 4)
__global__ __launch_bounds__(256) void xproj_gemm(
    const float* __restrict__ x, const uint4* __restrict__ wip4,
    const float* __restrict__ bi, const float* __restrict__ bh,
    _Float16* __restrict__ xph, int m0) {
  __shared__ _Float16 xl[16][128];
  const int tid = threadIdx.x;
  const int mt = blockIdx.x, gt = blockIdx.y;
  const int g = gt * 256 + tid;
#pragma unroll
  for (int i = 0; i < 8; ++i) {
    int idx = i * 256 + tid;          // 0..2047
    int p = idx >> 7, d = idx & 127;
    int m = m0 + mt * 16 + p;         // global m = t*64+b
    xl[p][d] = (_Float16)x[(size_t)(m & 63) * (T_TOT * DD) + (size_t)(m >> 6) * DD + d];
  }
  __syncthreads();
  float acc[16];
#pragma unroll
  for (int p = 0; p < 16; ++p) acc[p] = 0.f;
#pragma unroll
  for (int kp4 = 0; kp4 < 16; ++kp4) {
    uint4 w = wip4[kp4 * GG + g];
#pragma unroll
    for (int p = 0; p < 16; ++p) {
      uint4 hv = *(const uint4*)(&xl[p][kp4 * 8]);   // uniform addr -> broadcast
      acc[p] = fdot2(w.x, hv.x, acc[p]);
      acc[p] = fdot2(w.y, hv.y, acc[p]);
      acc[p] = fdot2(w.z, hv.z, acc[p]);
      acc[p] = fdot2(w.w, hv.w, acc[p]);
    }
  }
  float bsum = bi[g] + bh[g];
#pragma unroll
  for (int p = 0; p < 16; ++p) {
    int ml = mt * 16 + p;
    xph[(size_t)ml * GG + g] = (_Float16)(acc[p] + bsum);
  }
}

// ---------------- the scan: one block per batch element, 1024 threads (1 gate each)
// Wh: 92 f16-pairs in VGPRs + 36 pairs in LDS per gate. hx f16 in LDS (broadcast reads).
__global__ __launch_bounds__(1024) void lstm_scan(
    const uint4* __restrict__ whp4, const _Float16* __restrict__ xph,
    const float* __restrict__ lna_g, const float* __restrict__ lna_b,
    const float* __restrict__ ln_g, const float* __restrict__ ln_b,
    _Float16* __restrict__ hs16,
    _Float16* __restrict__ hxst, float* __restrict__ cxst,
    int t0, int ct) {
  extern __shared__ char smem[];
  u32* w_lds = (u32*)smem;                          // [36][1024] = 147456 B
  _Float16* hx16 = (_Float16*)(smem + 147456);      // [256]  (16B aligned)
  float* red = (float*)(smem + 147968);             // [32]
  float* red2 = red + 32;                           // [8]
  float* gact = red2 + 8;                           // [1024]

  const int b = blockIdx.x, tid = threadIdx.x;
  const int q = tid >> 8, h = tid & 255;
  const int wid = tid >> 6, lane = tid & 63;

  uint4 wr[23];
#pragma unroll
  for (int kb = 0; kb < 23; ++kb) wr[kb] = whp4[kb * 1024 + tid];
#pragma unroll
  for (int kb = 23; kb < 32; ++kb) {
    uint4 v = whp4[kb * 1024 + tid];
    int p = (kb - 23) * 4;
    w_lds[(p + 0) * 1024 + tid] = v.x;
    w_lds[(p + 1) * 1024 + tid] = v.y;
    w_lds[(p + 2) * 1024 + tid] = v.z;
    w_lds[(p + 3) * 1024 + tid] = v.w;
  }
  float lg = lna_g[tid], lbv = lna_b[tid];
  float lng = 0.f, lnb = 0.f, cx = 0.f;
  if (tid < HH) {
    lng = ln_g[tid]; lnb = ln_b[tid];
    if (t0 == 0) {
      hx16[tid] = (_Float16)0.f; cx = 0.f;
    } else {
      hx16[tid] = hxst[b * HH + tid]; cx = cxst[b * HH + tid];
    }
  }
  __syncthreads();

  const _Float16* xrow = xph + b * GG + tid;
  _Float16* hsp = hs16 + (size_t)b * HH + h;

  for (int tl = 0; tl < ct; ++tl) {
    float a0 = (float)xrow[(size_t)tl * (BB * GG)];
    float a1 = 0.f, a2 = 0.f, a3 = 0.f;
#pragma unroll
    for (int kb = 0; kb < 23; ++kb) {
      uint4 hv = *(const uint4*)(hx16 + kb * 8);   // broadcast
      a0 = fdot2(wr[kb].x, hv.x, a0);
      a1 = fdot2(wr[kb].y, hv.y, a1);
      a2 = fdot2(wr[kb].z, hv.z, a2);
      a3 = fdot2(wr[kb].w, hv.w, a3);
    }
#pragma unroll
    for (int kb = 23; kb < 32; ++kb) {
      uint4 hv = *(const uint4*)(hx16 + kb * 8);
      int p = (kb - 23) * 4;
      a0 = fdot2(w_lds[(p + 0) * 1024 + tid], hv.x, a0);
      a1 = fdot2(w_lds[(p + 1) * 1024 + tid], hv.y, a1);
      a2 = fdot2(w_lds[(p + 2) * 1024 + tid], hv.z, a2);
      a3 = fdot2(w_lds[(p + 3) * 1024 + tid], hv.w, a3);
    }
    float acc = (a0 + a1) + (a2 + a3);

    // gate-block LN over 256 gates (4 waves) per q
    float s = acc, ss = acc * acc;
#pragma unroll
    for (int m = 1; m <= 32; m <<= 1) {
      s += __shfl_xor(s, m, 64);
      ss += __shfl_xor(ss, m, 64);
    }
    if (lane == 0) { red[wid] = s; red[16 + wid] = ss; }
    __syncthreads();                                  // B1
    float S  = red[4 * q] + red[4 * q + 1] + red[4 * q + 2] + red[4 * q + 3];
    float SS = red[16 + 4 * q] + red[16 + 4 * q + 1] + red[16 + 4 * q + 2] + red[16 + 4 * q + 3];
    float mean = S * (1.f / HH);
    float var = SS * (1.f / HH) - mean * mean;
    float gn = (acc - mean) * rsqrtf(var + LN_EPS) * lg + lbv;
    float av = (q == 2) ? fast_tanh(gn) : fast_sigmoid(gn);
    gact[tid] = av;
    __syncthreads();                                  // B2

    float cy = 0.f;
    if (tid < HH) {
      cy = gact[HH + h] * cx + gact[h] * gact[2 * HH + h];
      cx = cy;
      float s2 = cy, ss2 = cy * cy;
#pragma unroll
      for (int m = 1; m <= 32; m <<= 1) {
        s2 += __shfl_xor(s2, m, 64);
        ss2 += __shfl_xor(ss2, m, 64);
      }
      if (lane == 0) { red2[wid] = s2; red2[4 + wid] = ss2; }
    }
    __syncthreads();                                  // B3
    if (tid < HH) {
      float S2 = red2[0] + red2[1] + red2[2] + red2[3];
      float SS2 = red2[4] + red2[5] + red2[6] + red2[7];
      float mc = S2 * (1.f / HH);
      float vc = SS2 * (1.f / HH) - mc * mc;
      float cyn = (cy - mc) * rsqrtf(vc + LN_EPS) * lng + lnb;
      float hy = gact[3 * HH + h] * fast_tanh(cyn);
      hx16[h] = (_Float16)hy;
      hsp[(size_t)(t0 + tl) * (BB * HH)] = (_Float16)hy;
    }
    __syncthreads();                                  // B4
  }
  if (tid < HH) { hxst[b * HH + tid] = hx16[tid]; cxst[b * HH + tid] = cx; }
}

// ---------------- out GEMM: out[b][t][o] = relu(sum_h hs[t][b][h]*Wf[o][h] + bf[o])
__global__ __launch_bounds__(256) void out_gemm(
    const _Float16* __restrict__ hs16, const float* __restrict__ Wf,
    const float* __restrict__ bf, float* __restrict__ out) {
  __shared__ u32 wfl[128][64];    // pairs [kp][o], 32KB
  __shared__ u32 hsl[16][132];    // pairs [p][kp], padded
  const int tid = threadIdx.x;
  const int mbase = blockIdx.x * 16;
#pragma unroll
  for (int i = 0; i < 32; ++i) {  // 8192 pairs of Wf
    int idx = i * 256 + tid;
    int kp = idx >> 6, o = idx & 63;
    wfl[kp][o] = pkf16(Wf[o * HH + kp * 2], Wf[o * HH + kp * 2 + 1]);
  }
#pragma unroll
  for (int i = 0; i < 8; ++i) {   // 2048 pairs of hs
    int idx = i * 256 + tid;
    int p = idx >> 7, kp = idx & 127;
    hsl[p][kp] = *(const u32*)(hs16 + (size_t)(mbase + p) * HH + kp * 2);
  }
  __syncthreads();
  const int o = tid & 63, mi = tid >> 6;
  float bfo = bf[o];
#pragma unroll
  for (int mm = mi; mm < 16; mm += 4) {
    float a0 = bfo, a1 = 0.f, a2 = 0.f, a3 = 0.f;
#pragma unroll
    for (int kp = 0; kp < 128; kp += 4) {
      a0 = fdot2(wfl[kp + 0][o], hsl[mm][kp + 0], a0);
      a1 = fdot2(wfl[kp + 1][o], hsl[mm][kp + 1], a1);
      a2 = fdot2(wfl[kp + 2][o], hsl[mm][kp + 2], a2);
      a3 = fdot2(wfl[kp + 3][o], hsl[mm][kp + 3], a3);
    }
    float r = (a0 + a1) + (a2 + a3);
    int m = mbase + mm;
    out[(size_t)(m & 63) * (T_TOT * OO) + (size_t)(m >> 6) * OO + o] = fmaxf(r, 0.f);
  }
}

extern "C" void kernel_launch(void* const* d_in, const int* in_sizes, int n_in,
                              void* d_out, int out_size, void* d_ws, size_t ws_size,
                              hipStream_t stream) {
  if (n_in < 11) return;
  const float* x    = (const float*)d_in[0];
  const float* Wi   = (const float*)d_in[1];
  const float* bi   = (const float*)d_in[2];
  const float* Wh   = (const float*)d_in[3];
  const float* bh   = (const float*)d_in[4];
  const float* lnag = (const float*)d_in[5];
  const float* lnab = (const float*)d_in[6];
  const float* lng  = (const float*)d_in[7];
  const float* lnb  = (const float*)d_in[8];
  const float* Wf   = (const float*)d_in[9];
  const float* bf   = (const float*)d_in[10];
  float* out = (float*)d_out;

  char* ws = (char*)d_ws;
  uint4* whp4 = (uint4*)ws;                                  // 512 KB
  uint4* wip4 = (uint4*)(ws + (512 << 10));                  // 256 KB
  _Float16* hs16 = (_Float16*)(ws + (1 << 20));              // 32 MB
  _Float16* hxst = (_Float16*)(ws + (1 << 20) + (32 << 20)); // 32 KB
  float* cxst = (float*)(ws + (1 << 20) + (32 << 20) + (64 << 10)); // 64 KB
  const size_t xph_off = (size_t)35 << 20;
  _Float16* xph = (_Float16*)(ws + xph_off);

  size_t avail = ws_size > xph_off ? ws_size - xph_off : 0;
  int ct = T_TOT;
  while (ct > 1 && (size_t)ct * (BB * GG * 2) > avail) ct >>= 1;

  (void)hipFuncSetAttribute(reinterpret_cast<const void*>(lstm_scan),
                            hipFuncAttributeMaxDynamicSharedMemorySize, 152224);

  prep_wh<<<128, 256, 0, stream>>>(Wh, whp4);
  prep_wi<<<64, 256, 0, stream>>>(Wi, wip4);
  for (int t0 = 0; t0 < T_TOT; t0 += ct) {
    xproj_gemm<<<dim3((ct * BB) / 16, 4), 256, 0, stream>>>(x, wip4, bi, bh, xph, t0 * BB);
    lstm_scan<<<BB, 1024, 152224, stream>>>(whp4, xph, lnag, lnab, lng, lnb,
                                            hs16, hxst, cxst, t0, ct);
  }
  out_gemm<<<(T_TOT * BB) / 16, 256, 0, stream>>>(hs16, Wf, bf, out);
}

// Round 2
// 3092.453 us; speedup vs baseline: 1.6556x; 1.6556x over previous
//
#include <hip/hip_runtime.h>

#define T_TOT 1024
#define BB 64
#define DD 128
#define HH 256
#define GG 1024
#define OO 64
#define LN_EPS 1e-3f
#define NV 24   // uint4 weight chunks per gate kept in VGPRs
#define NL 8    // uint4 weight chunks per gate kept in LDS (NV+NL=32)

typedef unsigned int u32;
typedef _Float16 h2 __attribute__((ext_vector_type(2)));

__device__ __forceinline__ float fdot2(u32 a, u32 b, float c) {
  return __builtin_amdgcn_fdot2(__builtin_bit_cast(h2, a), __builtin_bit_cast(h2, b), c, false);
}
__device__ __forceinline__ u32 pkf16(float lo, float hi) {
  h2 v = { (_Float16)lo, (_Float16)hi };
  return __builtin_bit_cast(u32, v);
}
__device__ __forceinline__ float fast_sigmoid(float x) { return 1.0f / (1.0f + __expf(-x)); }
__device__ __forceinline__ float fast_tanh(float x) { return 2.0f / (1.0f + __expf(-2.0f * x)) - 1.0f; }

// ---------------- prep: pack Wh (4H x H) into f16 pairs, chunked by 8 along H ----
// whp4[kb*1024 + g] = 8 f16 = Wh[g][8kb .. 8kb+7]
__global__ void prep_wh(const float* __restrict__ Wh, uint4* __restrict__ whp4) {
  int id = blockIdx.x * 256 + threadIdx.x;     // 32768
  int kb = id >> 10, g = id & 1023;
  const float* p = Wh + (size_t)g * HH + kb * 8;
  uint4 o;
  o.x = pkf16(p[0], p[1]); o.y = pkf16(p[2], p[3]);
  o.z = pkf16(p[4], p[5]); o.w = pkf16(p[6], p[7]);
  whp4[id] = o;
}

// wip4[kp4*1024 + g] = 8 f16 = Wi[g][8*kp4 .. +7]
__global__ void prep_wi(const float* __restrict__ Wi, uint4* __restrict__ wip4) {
  int id = blockIdx.x * 256 + threadIdx.x;     // 16384
  int kp4 = id >> 10, g = id & 1023;
  const float* p = Wi + (size_t)g * DD + kp4 * 8;
  uint4 o;
  o.x = pkf16(p[0], p[1]); o.y = pkf16(p[2], p[3]);
  o.z = pkf16(p[4], p[5]); o.w = pkf16(p[6], p[7]);
  wip4[id] = o;
}

// ---------------- xproj GEMM: xph[ml][g] = sum_d x[b][t][d]*Wi[g][d] + bi[g]+bh[g]
__global__ __launch_bounds__(256) void xproj_gemm(
    const float* __restrict__ x, const uint4* __restrict__ wip4,
    const float* __restrict__ bi, const float* __restrict__ bh,
    _Float16* __restrict__ xph, int m0) {
  __shared__ _Float16 xl[16][128];
  const int tid = threadIdx.x;
  const int mt = blockIdx.x, gt = blockIdx.y;
  const int g = gt * 256 + tid;
#pragma unroll
  for (int i = 0; i < 8; ++i) {
    int idx = i * 256 + tid;          // 0..2047
    int p = idx >> 7, d = idx & 127;
    int m = m0 + mt * 16 + p;         // global m = t*64+b
    xl[p][d] = (_Float16)x[(size_t)(m & 63) * (T_TOT * DD) + (size_t)(m >> 6) * DD + d];
  }
  __syncthreads();
  float acc[16];
#pragma unroll
  for (int p = 0; p < 16; ++p) acc[p] = 0.f;
#pragma unroll
  for (int kp4 = 0; kp4 < 16; ++kp4) {
    uint4 w = wip4[kp4 * GG + g];
#pragma unroll
    for (int p = 0; p < 16; ++p) {
      uint4 hv = *(const uint4*)(&xl[p][kp4 * 8]);   // uniform addr -> broadcast
      acc[p] = fdot2(w.x, hv.x, acc[p]);
      acc[p] = fdot2(w.y, hv.y, acc[p]);
      acc[p] = fdot2(w.z, hv.z, acc[p]);
      acc[p] = fdot2(w.w, hv.w, acc[p]);
    }
  }
  float bsum = bi[g] + bh[g];
#pragma unroll
  for (int p = 0; p < 16; ++p) {
    int ml = mt * 16 + p;
    xph[(size_t)ml * GG + g] = (_Float16)(acc[p] + bsum);
  }
}

// ---------------- scan v2: one block per batch, 512 threads, 2 gates/thread.
// Waves (2q, 2q+1) own LN-block q; gate gA = q*256 + r*128 + lane, gB = gA+64.
// Weights: NV uint4/gate in VGPR, NL uint4/gate in LDS ([j][tid] layout, conflict-free).
__global__ __launch_bounds__(512, 2) void lstm_scan(
    const uint4* __restrict__ whp4, const _Float16* __restrict__ xph,
    const float* __restrict__ lna_g, const float* __restrict__ lna_b,
    const float* __restrict__ ln_g, const float* __restrict__ ln_b,
    _Float16* __restrict__ hs16,
    _Float16* __restrict__ hxst, float* __restrict__ cxst,
    int t0, int ct) {
  extern __shared__ char smem[];
  uint4* wl = (uint4*)smem;                         // [2*NL][512] uint4 = 131072 B
  _Float16* hx16 = (_Float16*)(smem + 131072);      // 256 f16 = 512 B
  float* red  = (float*)(smem + 131584);            // 16 floats
  float* red2 = (float*)(smem + 131648);            // 8 floats
  float* gact = (float*)(smem + 131680);            // 1024 floats

  const int tid = threadIdx.x;
  const int b = blockIdx.x;
  const int lane = tid & 63, wid = tid >> 6;
  const int q = wid >> 1, r = wid & 1;
  const int gA = q * 256 + r * 128 + lane;
  const int gB = gA + 64;

  uint4 wrA[NV], wrB[NV];
#pragma unroll
  for (int kb = 0; kb < NV; ++kb) {
    wrA[kb] = whp4[kb * 1024 + gA];
    wrB[kb] = whp4[kb * 1024 + gB];
  }
#pragma unroll
  for (int j = 0; j < NL; ++j) {
    wl[j * 512 + tid]        = whp4[(NV + j) * 1024 + gA];
    wl[(NL + j) * 512 + tid] = whp4[(NV + j) * 1024 + gB];
  }
  float lgA = lna_g[gA], lbA = lna_b[gA];
  float lgB = lna_g[gB], lbB = lna_b[gB];
  float lng = 0.f, lnb = 0.f, cx = 0.f;
  if (tid < HH) {
    lng = ln_g[tid]; lnb = ln_b[tid];
    if (t0 == 0) {
      hx16[tid] = (_Float16)0.f;
    } else {
      hx16[tid] = hxst[b * HH + tid]; cx = cxst[b * HH + tid];
    }
  }
  __syncthreads();

  const _Float16* xrA = xph + b * GG + gA;
  const _Float16* xrB = xph + b * GG + gB;
  _Float16* hsp = hs16 + (size_t)b * HH + (tid & 255);

  _Float16 xA16 = xrA[0], xB16 = xrB[0];
  for (int tl = 0; tl < ct; ++tl) {
    float accA = (float)xA16, accB = (float)xB16;
    if (tl + 1 < ct) {   // prefetch next step's xproj
      xA16 = xrA[(size_t)(tl + 1) * (BB * GG)];
      xB16 = xrB[(size_t)(tl + 1) * (BB * GG)];
    }
#pragma unroll
    for (int kb = 0; kb < NV; ++kb) {
      uint4 hv = *(const uint4*)(hx16 + kb * 8);   // wave-uniform broadcast
      accA = fdot2(wrA[kb].x, hv.x, accA);
      accA = fdot2(wrA[kb].y, hv.y, accA);
      accA = fdot2(wrA[kb].z, hv.z, accA);
      accA = fdot2(wrA[kb].w, hv.w, accA);
      accB = fdot2(wrB[kb].x, hv.x, accB);
      accB = fdot2(wrB[kb].y, hv.y, accB);
      accB = fdot2(wrB[kb].z, hv.z, accB);
      accB = fdot2(wrB[kb].w, hv.w, accB);
    }
#pragma unroll
    for (int j = 0; j < NL; ++j) {
      uint4 hv = *(const uint4*)(hx16 + (NV + j) * 8);
      uint4 wA = wl[j * 512 + tid];
      uint4 wB = wl[(NL + j) * 512 + tid];
      accA = fdot2(wA.x, hv.x, accA);
      accA = fdot2(wA.y, hv.y, accA);
      accA = fdot2(wA.z, hv.z, accA);
      accA = fdot2(wA.w, hv.w, accA);
      accB = fdot2(wB.x, hv.x, accB);
      accB = fdot2(wB.y, hv.y, accB);
      accB = fdot2(wB.z, hv.z, accB);
      accB = fdot2(wB.w, hv.w, accB);
    }

    // gate-block LN over 256 gates = waves {2q, 2q+1}
    float s = accA + accB, ss = accA * accA + accB * accB;
#pragma unroll
    for (int m = 1; m <= 32; m <<= 1) {
      s += __shfl_xor(s, m, 64);
      ss += __shfl_xor(ss, m, 64);
    }
    if (lane == 0) { red[wid] = s; red[8 + wid] = ss; }
    __syncthreads();                                  // B1
    float S  = red[2 * q] + red[2 * q + 1];
    float SS = red[8 + 2 * q] + red[8 + 2 * q + 1];
    float mean = S * (1.f / HH);
    float var = SS * (1.f / HH) - mean * mean;
    float rstd = rsqrtf(var + LN_EPS);
    float gnA = (accA - mean) * rstd * lgA + lbA;
    float gnB = (accB - mean) * rstd * lgB + lbB;
    float avA, avB;
    if (q == 2) { avA = fast_tanh(gnA); avB = fast_tanh(gnB); }      // wave-uniform branch
    else        { avA = fast_sigmoid(gnA); avB = fast_sigmoid(gnB); }
    gact[gA] = avA; gact[gB] = avB;
    __syncthreads();                                  // B2

    float cy = 0.f;
    if (tid < HH) {
      int h = tid;
      cy = gact[HH + h] * cx + gact[h] * gact[2 * HH + h];
      cx = cy;
      float s2 = cy, ss2 = cy * cy;
#pragma unroll
      for (int m = 1; m <= 32; m <<= 1) {
        s2 += __shfl_xor(s2, m, 64);
        ss2 += __shfl_xor(ss2, m, 64);
      }
      if (lane == 0) { red2[wid] = s2; red2[4 + wid] = ss2; }
    }
    __syncthreads();                                  // B3
    if (tid < HH) {
      int h = tid;
      float S2  = red2[0] + red2[1] + red2[2] + red2[3];
      float SS2 = red2[4] + red2[5] + red2[6] + red2[7];
      float mc = S2 * (1.f / HH);
      float vc = SS2 * (1.f / HH) - mc * mc;
      float cyn = (cy - mc) * rsqrtf(vc + LN_EPS) * lng + lnb;
      float hy = gact[3 * HH + h] * fast_tanh(cyn);
      hx16[h] = (_Float16)hy;
      hsp[(size_t)(t0 + tl) * (BB * HH)] = (_Float16)hy;
    }
    __syncthreads();                                  // B4
  }
  if (tid < HH) { hxst[b * HH + tid] = hx16[tid]; cxst[b * HH + tid] = cx; }
}

// ---------------- out GEMM: out[b][t][o] = relu(sum_h hs[t][b][h]*Wf[o][h] + bf[o])
__global__ __launch_bounds__(256) void out_gemm(
    const _Float16* __restrict__ hs16, const float* __restrict__ Wf,
    const float* __restrict__ bf, float* __restrict__ out) {
  __shared__ u32 wfl[128][64];    // pairs [kp][o], 32KB
  __shared__ u32 hsl[16][132];    // pairs [p][kp], padded
  const int tid = threadIdx.x;
  const int mbase = blockIdx.x * 16;
#pragma unroll
  for (int i = 0; i < 32; ++i) {  // 8192 pairs of Wf
    int idx = i * 256 + tid;
    int kp = idx >> 6, o = idx & 63;
    wfl[kp][o] = pkf16(Wf[o * HH + kp * 2], Wf[o * HH + kp * 2 + 1]);
  }
#pragma unroll
  for (int i = 0; i < 8; ++i) {   // 2048 pairs of hs
    int idx = i * 256 + tid;
    int p = idx >> 7, kp = idx & 127;
    hsl[p][kp] = *(const u32*)(hs16 + (size_t)(mbase + p) * HH + kp * 2);
  }
  __syncthreads();
  const int o = tid & 63, mi = tid >> 6;
  float bfo = bf[o];
#pragma unroll
  for (int mm = mi; mm < 16; mm += 4) {
    float a0 = bfo, a1 = 0.f, a2 = 0.f, a3 = 0.f;
#pragma unroll
    for (int kp = 0; kp < 128; kp += 4) {
      a0 = fdot2(wfl[kp + 0][o], hsl[mm][kp + 0], a0);
      a1 = fdot2(wfl[kp + 1][o], hsl[mm][kp + 1], a1);
      a2 = fdot2(wfl[kp + 2][o], hsl[mm][kp + 2], a2);
      a3 = fdot2(wfl[kp + 3][o], hsl[mm][kp + 3], a3);
    }
    float r = (a0 + a1) + (a2 + a3);
    int m = mbase + mm;
    out[(size_t)(m & 63) * (T_TOT * OO) + (size_t)(m >> 6) * OO + o] = fmaxf(r, 0.f);
  }
}

extern "C" void kernel_launch(void* const* d_in, const int* in_sizes, int n_in,
                              void* d_out, int out_size, void* d_ws, size_t ws_size,
                              hipStream_t stream) {
  if (n_in < 11) return;
  const float* x    = (const float*)d_in[0];
  const float* Wi   = (const float*)d_in[1];
  const float* bi   = (const float*)d_in[2];
  const float* Wh   = (const float*)d_in[3];
  const float* bh   = (const float*)d_in[4];
  const float* lnag = (const float*)d_in[5];
  const float* lnab = (const float*)d_in[6];
  const float* lng  = (const float*)d_in[7];
  const float* lnb  = (const float*)d_in[8];
  const float* Wf   = (const float*)d_in[9];
  const float* bf   = (const float*)d_in[10];
  float* out = (float*)d_out;

  char* ws = (char*)d_ws;
  uint4* whp4 = (uint4*)ws;                                  // 512 KB
  uint4* wip4 = (uint4*)(ws + (512 << 10));                  // 256 KB
  _Float16* hs16 = (_Float16*)(ws + (1 << 20));              // 32 MB
  _Float16* hxst = (_Float16*)(ws + (1 << 20) + (32 << 20)); // 32 KB
  float* cxst = (float*)(ws + (1 << 20) + (32 << 20) + (64 << 10)); // 64 KB
  const size_t xph_off = (size_t)35 << 20;
  _Float16* xph = (_Float16*)(ws + xph_off);

  size_t avail = ws_size > xph_off ? ws_size - xph_off : 0;
  int ct = T_TOT;
  while (ct > 1 && (size_t)ct * (BB * GG * 2) > avail) ct >>= 1;

  const int scan_smem = 135776;   // 131072 wl + 512 hx + 96 red + pad + 4096 gact
  (void)hipFuncSetAttribute(reinterpret_cast<const void*>(lstm_scan),
                            hipFuncAttributeMaxDynamicSharedMemorySize, scan_smem);

  prep_wh<<<128, 256, 0, stream>>>(Wh, whp4);
  prep_wi<<<64, 256, 0, stream>>>(Wi, wip4);
  for (int t0 = 0; t0 < T_TOT; t0 += ct) {
    xproj_gemm<<<dim3((ct * BB) / 16, 4), 256, 0, stream>>>(x, wip4, bi, bh, xph, t0 * BB);
    lstm_scan<<<BB, 512, scan_smem, stream>>>(whp4, xph, lnag, lnab, lng, lnb,
                                              hs16, hxst, cxst, t0, ct);
  }
  out_gemm<<<(T_TOT * BB) / 16, 256, 0, stream>>>(hs16, Wf, bf, out);
}

// Round 3
// 3089.680 us; speedup vs baseline: 1.6571x; 1.0009x over previous
//
#include <hip/hip_runtime.h>

#define T_TOT 1024
#define BB 64
#define DD 128
#define HH 256
#define GG 1024
#define OO 64
#define LN_EPS 1e-3f
#define NV 24   // uint4 weight chunks per gate kept in VGPRs
#define NL 8    // uint4 weight chunks per gate kept in LDS (NV+NL=32)

typedef unsigned int u32;
typedef _Float16 h2 __attribute__((ext_vector_type(2)));

__device__ __forceinline__ float fdot2(u32 a, u32 b, float c) {
  return __builtin_amdgcn_fdot2(__builtin_bit_cast(h2, a), __builtin_bit_cast(h2, b), c, false);
}
__device__ __forceinline__ u32 pkf16(float lo, float hi) {
  h2 v = { (_Float16)lo, (_Float16)hi };
  return __builtin_bit_cast(u32, v);
}
__device__ __forceinline__ float fast_sigmoid(float x) { return 1.0f / (1.0f + __expf(-x)); }
__device__ __forceinline__ float fast_tanh(float x) { return 2.0f / (1.0f + __expf(-2.0f * x)) - 1.0f; }

// ---------------- prep: pack Wh (4H x H) into f16 pairs, chunked by 8 along H ----
__global__ void prep_wh(const float* __restrict__ Wh, uint4* __restrict__ whp4) {
  int id = blockIdx.x * 256 + threadIdx.x;     // 32768
  int kb = id >> 10, g = id & 1023;
  const float* p = Wh + (size_t)g * HH + kb * 8;
  uint4 o;
  o.x = pkf16(p[0], p[1]); o.y = pkf16(p[2], p[3]);
  o.z = pkf16(p[4], p[5]); o.w = pkf16(p[6], p[7]);
  whp4[id] = o;
}

__global__ void prep_wi(const float* __restrict__ Wi, uint4* __restrict__ wip4) {
  int id = blockIdx.x * 256 + threadIdx.x;     // 16384
  int kp4 = id >> 10, g = id & 1023;
  const float* p = Wi + (size_t)g * DD + kp4 * 8;
  uint4 o;
  o.x = pkf16(p[0], p[1]); o.y = pkf16(p[2], p[3]);
  o.z = pkf16(p[4], p[5]); o.w = pkf16(p[6], p[7]);
  wip4[id] = o;
}

// ---------------- xproj GEMM: xph[ml][g] = sum_d x[b][t][d]*Wi[g][d] + bi[g]+bh[g]
__global__ __launch_bounds__(256) void xproj_gemm(
    const float* __restrict__ x, const uint4* __restrict__ wip4,
    const float* __restrict__ bi, const float* __restrict__ bh,
    _Float16* __restrict__ xph, int m0) {
  __shared__ _Float16 xl[16][128];
  const int tid = threadIdx.x;
  const int mt = blockIdx.x, gt = blockIdx.y;
  const int g = gt * 256 + tid;
#pragma unroll
  for (int i = 0; i < 8; ++i) {
    int idx = i * 256 + tid;          // 0..2047
    int p = idx >> 7, d = idx & 127;
    int m = m0 + mt * 16 + p;         // global m = t*64+b
    xl[p][d] = (_Float16)x[(size_t)(m & 63) * (T_TOT * DD) + (size_t)(m >> 6) * DD + d];
  }
  __syncthreads();
  float acc[16];
#pragma unroll
  for (int p = 0; p < 16; ++p) acc[p] = 0.f;
#pragma unroll
  for (int kp4 = 0; kp4 < 16; ++kp4) {
    uint4 w = wip4[kp4 * GG + g];
#pragma unroll
    for (int p = 0; p < 16; ++p) {
      uint4 hv = *(const uint4*)(&xl[p][kp4 * 8]);   // uniform addr -> broadcast
      acc[p] = fdot2(w.x, hv.x, acc[p]);
      acc[p] = fdot2(w.y, hv.y, acc[p]);
      acc[p] = fdot2(w.z, hv.z, acc[p]);
      acc[p] = fdot2(w.w, hv.w, acc[p]);
    }
  }
  float bsum = bi[g] + bh[g];
#pragma unroll
  for (int p = 0; p < 16; ++p) {
    int ml = mt * 16 + p;
    xph[(size_t)ml * GG + g] = (_Float16)(acc[p] + bsum);
  }
}

// ---------------- scan v3: one block per batch, 512 threads, 2 gates/thread.
// amdgpu_waves_per_eu(2,2): pin occupancy to exactly 2 waves/EU so the
// allocator may use the full 256-VGPR budget (grid=64 < #CU, extra
// occupancy is worthless; 128-VGPR alloc spilled the weight arrays).
__global__ __launch_bounds__(512, 2) __attribute__((amdgpu_waves_per_eu(2, 2)))
void lstm_scan(
    const uint4* __restrict__ whp4, const _Float16* __restrict__ xph,
    const float* __restrict__ lna_g, const float* __restrict__ lna_b,
    const float* __restrict__ ln_g, const float* __restrict__ ln_b,
    _Float16* __restrict__ hs16,
    _Float16* __restrict__ hxst, float* __restrict__ cxst,
    int t0, int ct) {
  extern __shared__ char smem[];
  uint4* wl = (uint4*)smem;                         // [2*NL][512] uint4 = 131072 B
  _Float16* hx16 = (_Float16*)(smem + 131072);      // 256 f16 = 512 B
  float* red  = (float*)(smem + 131584);            // 16 floats
  float* red2 = (float*)(smem + 131648);            // 8 floats
  float* gact = (float*)(smem + 131680);            // 1024 floats

  const int tid = threadIdx.x;
  const int b = blockIdx.x;
  const int lane = tid & 63, wid = tid >> 6;
  const int q = wid >> 1, r = wid & 1;
  const int gA = q * 256 + r * 128 + lane;
  const int gB = gA + 64;

  uint4 wrA[NV], wrB[NV];
#pragma unroll
  for (int kb = 0; kb < NV; ++kb) {
    wrA[kb] = whp4[kb * 1024 + gA];
    wrB[kb] = whp4[kb * 1024 + gB];
  }
#pragma unroll
  for (int j = 0; j < NL; ++j) {
    wl[j * 512 + tid]        = whp4[(NV + j) * 1024 + gA];
    wl[(NL + j) * 512 + tid] = whp4[(NV + j) * 1024 + gB];
  }
  float lgA = lna_g[gA], lbA = lna_b[gA];
  float lgB = lna_g[gB], lbB = lna_b[gB];
  float lng = 0.f, lnb = 0.f, cx = 0.f;
  if (tid < HH) {
    lng = ln_g[tid]; lnb = ln_b[tid];
    if (t0 == 0) {
      hx16[tid] = (_Float16)0.f;
    } else {
      hx16[tid] = hxst[b * HH + tid]; cx = cxst[b * HH + tid];
    }
  }
  __syncthreads();

  const _Float16* xrA = xph + b * GG + gA;
  const _Float16* xrB = xph + b * GG + gB;
  _Float16* hsp = hs16 + (size_t)b * HH + (tid & 255);

  _Float16 xA16 = xrA[0], xB16 = xrB[0];
  for (int tl = 0; tl < ct; ++tl) {
    float accA = (float)xA16, accB = (float)xB16;
    if (tl + 1 < ct) {   // prefetch next step's xproj
      xA16 = xrA[(size_t)(tl + 1) * (BB * GG)];
      xB16 = xrB[(size_t)(tl + 1) * (BB * GG)];
    }
#pragma unroll
    for (int kb = 0; kb < NV; ++kb) {
      uint4 hv = *(const uint4*)(hx16 + kb * 8);   // wave-uniform broadcast
      accA = fdot2(wrA[kb].x, hv.x, accA);
      accA = fdot2(wrA[kb].y, hv.y, accA);
      accA = fdot2(wrA[kb].z, hv.z, accA);
      accA = fdot2(wrA[kb].w, hv.w, accA);
      accB = fdot2(wrB[kb].x, hv.x, accB);
      accB = fdot2(wrB[kb].y, hv.y, accB);
      accB = fdot2(wrB[kb].z, hv.z, accB);
      accB = fdot2(wrB[kb].w, hv.w, accB);
    }
#pragma unroll
    for (int j = 0; j < NL; ++j) {
      uint4 hv = *(const uint4*)(hx16 + (NV + j) * 8);
      uint4 wA = wl[j * 512 + tid];
      uint4 wB = wl[(NL + j) * 512 + tid];
      accA = fdot2(wA.x, hv.x, accA);
      accA = fdot2(wA.y, hv.y, accA);
      accA = fdot2(wA.z, hv.z, accA);
      accA = fdot2(wA.w, hv.w, accA);
      accB = fdot2(wB.x, hv.x, accB);
      accB = fdot2(wB.y, hv.y, accB);
      accB = fdot2(wB.z, hv.z, accB);
      accB = fdot2(wB.w, hv.w, accB);
    }

    // gate-block LN over 256 gates = waves {2q, 2q+1}
    float s = accA + accB, ss = accA * accA + accB * accB;
#pragma unroll
    for (int m = 1; m <= 32; m <<= 1) {
      s += __shfl_xor(s, m, 64);
      ss += __shfl_xor(ss, m, 64);
    }
    if (lane == 0) { red[wid] = s; red[8 + wid] = ss; }
    __syncthreads();                                  // B1
    float S  = red[2 * q] + red[2 * q + 1];
    float SS = red[8 + 2 * q] + red[8 + 2 * q + 1];
    float mean = S * (1.f / HH);
    float var = SS * (1.f / HH) - mean * mean;
    float rstd = rsqrtf(var + LN_EPS);
    float gnA = (accA - mean) * rstd * lgA + lbA;
    float gnB = (accB - mean) * rstd * lgB + lbB;
    float avA, avB;
    if (q == 2) { avA = fast_tanh(gnA); avB = fast_tanh(gnB); }      // wave-uniform branch
    else        { avA = fast_sigmoid(gnA); avB = fast_sigmoid(gnB); }
    gact[gA] = avA; gact[gB] = avB;
    __syncthreads();                                  // B2

    float cy = 0.f;
    if (tid < HH) {
      int h = tid;
      cy = gact[HH + h] * cx + gact[h] * gact[2 * HH + h];
      cx = cy;
      float s2 = cy, ss2 = cy * cy;
#pragma unroll
      for (int m = 1; m <= 32; m <<= 1) {
        s2 += __shfl_xor(s2, m, 64);
        ss2 += __shfl_xor(ss2, m, 64);
      }
      if (lane == 0) { red2[wid] = s2; red2[4 + wid] = ss2; }
    }
    __syncthreads();                                  // B3
    if (tid < HH) {
      int h = tid;
      float S2  = red2[0] + red2[1] + red2[2] + red2[3];
      float SS2 = red2[4] + red2[5] + red2[6] + red2[7];
      float mc = S2 * (1.f / HH);
      float vc = SS2 * (1.f / HH) - mc * mc;
      float cyn = (cy - mc) * rsqrtf(vc + LN_EPS) * lng + lnb;
      float hy = gact[3 * HH + h] * fast_tanh(cyn);
      hx16[h] = (_Float16)hy;
      hsp[(size_t)(t0 + tl) * (BB * HH)] = (_Float16)hy;
    }
    __syncthreads();                                  // B4
  }
  if (tid < HH) { hxst[b * HH + tid] = hx16[tid]; cxst[b * HH + tid] = cx; }
}

// ---------------- out GEMM: out[b][t][o] = relu(sum_h hs[t][b][h]*Wf[o][h] + bf[o])
__global__ __launch_bounds__(256) void out_gemm(
    const _Float16* __restrict__ hs16, const float* __restrict__ Wf,
    const float* __restrict__ bf, float* __restrict__ out) {
  __shared__ u32 wfl[128][64];    // pairs [kp][o], 32KB
  __shared__ u32 hsl[16][132];    // pairs [p][kp], padded
  const int tid = threadIdx.x;
  const int mbase = blockIdx.x * 16;
#pragma unroll
  for (int i = 0; i < 32; ++i) {  // 8192 pairs of Wf
    int idx = i * 256 + tid;
    int kp = idx >> 6, o = idx & 63;
    wfl[kp][o] = pkf16(Wf[o * HH + kp * 2], Wf[o * HH + kp * 2 + 1]);
  }
#pragma unroll
  for (int i = 0; i < 8; ++i) {   // 2048 pairs of hs
    int idx = i * 256 + tid;
    int p = idx >> 7, kp = idx & 127;
    hsl[p][kp] = *(const u32*)(hs16 + (size_t)(mbase + p) * HH + kp * 2);
  }
  __syncthreads();
  const int o = tid & 63, mi = tid >> 6;
  float bfo = bf[o];
#pragma unroll
  for (int mm = mi; mm < 16; mm += 4) {
    float a0 = bfo, a1 = 0.f, a2 = 0.f, a3 = 0.f;
#pragma unroll
    for (int kp = 0; kp < 128; kp += 4) {
      a0 = fdot2(wfl[kp + 0][o], hsl[mm][kp + 0], a0);
      a1 = fdot2(wfl[kp + 1][o], hsl[mm][kp + 1], a1);
      a2 = fdot2(wfl[kp + 2][o], hsl[mm][kp + 2], a2);
      a3 = fdot2(wfl[kp + 3][o], hsl[mm][kp + 3], a3);
    }
    float r = (a0 + a1) + (a2 + a3);
    int m = mbase + mm;
    out[(size_t)(m & 63) * (T_TOT * OO) + (size_t)(m >> 6) * OO + o] = fmaxf(r, 0.f);
  }
}

extern "C" void kernel_launch(void* const* d_in, const int* in_sizes, int n_in,
                              void* d_out, int out_size, void* d_ws, size_t ws_size,
                              hipStream_t stream) {
  if (n_in < 11) return;
  const float* x    = (const float*)d_in[0];
  const float* Wi   = (const float*)d_in[1];
  const float* bi   = (const float*)d_in[2];
  const float* Wh   = (const float*)d_in[3];
  const float* bh   = (const float*)d_in[4];
  const float* lnag = (const float*)d_in[5];
  const float* lnab = (const float*)d_in[6];
  const float* lng  = (const float*)d_in[7];
  const float* lnb  = (const float*)d_in[8];
  const float* Wf   = (const float*)d_in[9];
  const float* bf   = (const float*)d_in[10];
  float* out = (float*)d_out;

  char* ws = (char*)d_ws;
  uint4* whp4 = (uint4*)ws;                                  // 512 KB
  uint4* wip4 = (uint4*)(ws + (512 << 10));                  // 256 KB
  _Float16* hs16 = (_Float16*)(ws + (1 << 20));              // 32 MB
  _Float16* hxst = (_Float16*)(ws + (1 << 20) + (32 << 20)); // 32 KB
  float* cxst = (float*)(ws + (1 << 20) + (32 << 20) + (64 << 10)); // 64 KB
  const size_t xph_off = (size_t)35 << 20;
  _Float16* xph = (_Float16*)(ws + xph_off);

  size_t avail = ws_size > xph_off ? ws_size - xph_off : 0;
  int ct = T_TOT;
  while (ct > 1 && (size_t)ct * (BB * GG * 2) > avail) ct >>= 1;

  const int scan_smem = 135776;   // 131072 wl + 512 hx + 96 red + pad + 4096 gact
  (void)hipFuncSetAttribute(reinterpret_cast<const void*>(lstm_scan),
                            hipFuncAttributeMaxDynamicSharedMemorySize, scan_smem);

  prep_wh<<<128, 256, 0, stream>>>(Wh, whp4);
  prep_wi<<<64, 256, 0, stream>>>(Wi, wip4);
  for (int t0 = 0; t0 < T_TOT; t0 += ct) {
    xproj_gemm<<<dim3((ct * BB) / 16, 4), 256, 0, stream>>>(x, wip4, bi, bh, xph, t0 * BB);
    lstm_scan<<<BB, 512, scan_smem, stream>>>(whp4, xph, lnag, lnab, lng, lnb,
                                              hs16, hxst, cxst, t0, ct);
  }
  out_gemm<<<(T_TOT * BB) / 16, 256, 0, stream>>>(hs16, Wf, bf, out);
}

// Round 4
// 3012.082 us; speedup vs baseline: 1.6998x; 1.0258x over previous
//
#include <hip/hip_runtime.h>

#define T_TOT 1024
#define BB 64
#define DD 128
#define HH 256
#define GG 1024
#define OO 64
#define LN_EPS 1e-3f
#define NV 23   // uint4 weight chunks per gate kept in VGPRs (184 VGPRs for 2 gates)
#define NL 9    // uint4 weight chunks per gate kept in LDS (NV+NL=32)

typedef unsigned int u32;
typedef _Float16 h2 __attribute__((ext_vector_type(2)));

__device__ __forceinline__ float fdot2(u32 a, u32 b, float c) {
  return __builtin_amdgcn_fdot2(__builtin_bit_cast(h2, a), __builtin_bit_cast(h2, b), c, false);
}
__device__ __forceinline__ u32 pkf16(float lo, float hi) {
  h2 v = { (_Float16)lo, (_Float16)hi };
  return __builtin_bit_cast(u32, v);
}
__device__ __forceinline__ float fast_sigmoid(float x) { return 1.0f / (1.0f + __expf(-x)); }
__device__ __forceinline__ float fast_tanh(float x) { return 2.0f / (1.0f + __expf(-2.0f * x)) - 1.0f; }

// ---------------- prep: pack Wh (4H x H) into f16 pairs, chunked by 8 along H ----
__global__ void prep_wh(const float* __restrict__ Wh, uint4* __restrict__ whp4) {
  int id = blockIdx.x * 256 + threadIdx.x;     // 32768
  int kb = id >> 10, g = id & 1023;
  const float* p = Wh + (size_t)g * HH + kb * 8;
  uint4 o;
  o.x = pkf16(p[0], p[1]); o.y = pkf16(p[2], p[3]);
  o.z = pkf16(p[4], p[5]); o.w = pkf16(p[6], p[7]);
  whp4[id] = o;
}

__global__ void prep_wi(const float* __restrict__ Wi, uint4* __restrict__ wip4) {
  int id = blockIdx.x * 256 + threadIdx.x;     // 16384
  int kp4 = id >> 10, g = id & 1023;
  const float* p = Wi + (size_t)g * DD + kp4 * 8;
  uint4 o;
  o.x = pkf16(p[0], p[1]); o.y = pkf16(p[2], p[3]);
  o.z = pkf16(p[4], p[5]); o.w = pkf16(p[6], p[7]);
  wip4[id] = o;
}

// ---------------- xproj GEMM: xph[ml][g] = sum_d x[b][t][d]*Wi[g][d] + bi[g]+bh[g]
__global__ __launch_bounds__(256) void xproj_gemm(
    const float* __restrict__ x, const uint4* __restrict__ wip4,
    const float* __restrict__ bi, const float* __restrict__ bh,
    _Float16* __restrict__ xph, int m0) {
  __shared__ _Float16 xl[16][128];
  const int tid = threadIdx.x;
  const int mt = blockIdx.x, gt = blockIdx.y;
  const int g = gt * 256 + tid;
#pragma unroll
  for (int i = 0; i < 8; ++i) {
    int idx = i * 256 + tid;          // 0..2047
    int p = idx >> 7, d = idx & 127;
    int m = m0 + mt * 16 + p;         // global m = t*64+b
    xl[p][d] = (_Float16)x[(size_t)(m & 63) * (T_TOT * DD) + (size_t)(m >> 6) * DD + d];
  }
  __syncthreads();
  float acc[16];
#pragma unroll
  for (int p = 0; p < 16; ++p) acc[p] = 0.f;
#pragma unroll
  for (int kp4 = 0; kp4 < 16; ++kp4) {
    uint4 w = wip4[kp4 * GG + g];
#pragma unroll
    for (int p = 0; p < 16; ++p) {
      uint4 hv = *(const uint4*)(&xl[p][kp4 * 8]);   // uniform addr -> broadcast
      acc[p] = fdot2(w.x, hv.x, acc[p]);
      acc[p] = fdot2(w.y, hv.y, acc[p]);
      acc[p] = fdot2(w.z, hv.z, acc[p]);
      acc[p] = fdot2(w.w, hv.w, acc[p]);
    }
  }
  float bsum = bi[g] + bh[g];
#pragma unroll
  for (int p = 0; p < 16; ++p) {
    int ml = mt * 16 + p;
    xph[(size_t)ml * GG + g] = (_Float16)(acc[p] + bsum);
  }
}

// ---------------- scan v4: one block per batch, 512 threads, 2 gates/thread.
// Occupancy pinned via a SINGLE directive pair (no __launch_bounds__ min-waves
// arg, which emitted a conflicting/ignored waves-per-eu attr): 2 waves/EU
// exactly -> 256-VGPR budget so the 184 weight VGPRs stay resident.
__global__ __attribute__((amdgpu_flat_work_group_size(512, 512), amdgpu_waves_per_eu(2, 2)))
void lstm_scan(
    const uint4* __restrict__ whp4, const _Float16* __restrict__ xph,
    const float* __restrict__ lna_g, const float* __restrict__ lna_b,
    const float* __restrict__ ln_g, const float* __restrict__ ln_b,
    _Float16* __restrict__ hs16,
    _Float16* __restrict__ hxst, float* __restrict__ cxst,
    int t0, int ct) {
  extern __shared__ char smem[];
  uint4* wl = (uint4*)smem;                         // [2*NL][512] uint4 = 147456 B
  _Float16* hx16 = (_Float16*)(smem + 147456);      // 256 f16 = 512 B
  float* red  = (float*)(smem + 147968);            // 16 floats
  float* red2 = (float*)(smem + 148032);            // 8 floats
  float* gact = (float*)(smem + 148064);            // 1024 floats -> end 152160

  const int tid = threadIdx.x;
  const int b = blockIdx.x;
  const int lane = tid & 63, wid = tid >> 6;
  const int q = wid >> 1, r = wid & 1;
  const int gA = q * 256 + r * 128 + lane;
  const int gB = gA + 64;

  uint4 wrA[NV], wrB[NV];
#pragma unroll
  for (int kb = 0; kb < NV; ++kb) {
    wrA[kb] = whp4[kb * 1024 + gA];
    wrB[kb] = whp4[kb * 1024 + gB];
  }
#pragma unroll
  for (int j = 0; j < NL; ++j) {
    wl[j * 512 + tid]        = whp4[(NV + j) * 1024 + gA];
    wl[(NL + j) * 512 + tid] = whp4[(NV + j) * 1024 + gB];
  }
  float lgA = lna_g[gA], lbA = lna_b[gA];
  float lgB = lna_g[gB], lbB = lna_b[gB];
  float lng = 0.f, lnb = 0.f, cx = 0.f;
  if (tid < HH) {
    lng = ln_g[tid]; lnb = ln_b[tid];
    if (t0 == 0) {
      hx16[tid] = (_Float16)0.f;
    } else {
      hx16[tid] = hxst[b * HH + tid]; cx = cxst[b * HH + tid];
    }
  }
  __syncthreads();

  const _Float16* xrA = xph + b * GG + gA;
  const _Float16* xrB = xph + b * GG + gB;
  _Float16* hsp = hs16 + (size_t)b * HH + (tid & 255);

  _Float16 xA16 = xrA[0], xB16 = xrB[0];
  for (int tl = 0; tl < ct; ++tl) {
    float accA = (float)xA16, accB = (float)xB16;
    if (tl + 1 < ct) {   // prefetch next step's xproj
      xA16 = xrA[(size_t)(tl + 1) * (BB * GG)];
      xB16 = xrB[(size_t)(tl + 1) * (BB * GG)];
    }
#pragma unroll
    for (int kb = 0; kb < NV; ++kb) {
      uint4 hv = *(const uint4*)(hx16 + kb * 8);   // wave-uniform broadcast
      accA = fdot2(wrA[kb].x, hv.x, accA);
      accA = fdot2(wrA[kb].y, hv.y, accA);
      accA = fdot2(wrA[kb].z, hv.z, accA);
      accA = fdot2(wrA[kb].w, hv.w, accA);
      accB = fdot2(wrB[kb].x, hv.x, accB);
      accB = fdot2(wrB[kb].y, hv.y, accB);
      accB = fdot2(wrB[kb].z, hv.z, accB);
      accB = fdot2(wrB[kb].w, hv.w, accB);
    }
#pragma unroll
    for (int j = 0; j < NL; ++j) {
      uint4 hv = *(const uint4*)(hx16 + (NV + j) * 8);
      uint4 wA = wl[j * 512 + tid];
      uint4 wB = wl[(NL + j) * 512 + tid];
      accA = fdot2(wA.x, hv.x, accA);
      accA = fdot2(wA.y, hv.y, accA);
      accA = fdot2(wA.z, hv.z, accA);
      accA = fdot2(wA.w, hv.w, accA);
      accB = fdot2(wB.x, hv.x, accB);
      accB = fdot2(wB.y, hv.y, accB);
      accB = fdot2(wB.z, hv.z, accB);
      accB = fdot2(wB.w, hv.w, accB);
    }

    // gate-block LN over 256 gates = waves {2q, 2q+1}
    float s = accA + accB, ss = accA * accA + accB * accB;
#pragma unroll
    for (int m = 1; m <= 32; m <<= 1) {
      s += __shfl_xor(s, m, 64);
      ss += __shfl_xor(ss, m, 64);
    }
    if (lane == 0) { red[wid] = s; red[8 + wid] = ss; }
    __syncthreads();                                  // B1
    float S  = red[2 * q] + red[2 * q + 1];
    float SS = red[8 + 2 * q] + red[8 + 2 * q + 1];
    float mean = S * (1.f / HH);
    float var = SS * (1.f / HH) - mean * mean;
    float rstd = rsqrtf(var + LN_EPS);
    float gnA = (accA - mean) * rstd * lgA + lbA;
    float gnB = (accB - mean) * rstd * lgB + lbB;
    float avA, avB;
    if (q == 2) { avA = fast_tanh(gnA); avB = fast_tanh(gnB); }      // wave-uniform branch
    else        { avA = fast_sigmoid(gnA); avB = fast_sigmoid(gnB); }
    gact[gA] = avA; gact[gB] = avB;
    __syncthreads();                                  // B2

    float cy = 0.f;
    if (tid < HH) {
      int h = tid;
      cy = gact[HH + h] * cx + gact[h] * gact[2 * HH + h];
      cx = cy;
      float s2 = cy, ss2 = cy * cy;
#pragma unroll
      for (int m = 1; m <= 32; m <<= 1) {
        s2 += __shfl_xor(s2, m, 64);
        ss2 += __shfl_xor(ss2, m, 64);
      }
      if (lane == 0) { red2[wid] = s2; red2[4 + wid] = ss2; }
    }
    __syncthreads();                                  // B3
    if (tid < HH) {
      int h = tid;
      float S2  = red2[0] + red2[1] + red2[2] + red2[3];
      float SS2 = red2[4] + red2[5] + red2[6] + red2[7];
      float mc = S2 * (1.f / HH);
      float vc = SS2 * (1.f / HH) - mc * mc;
      float cyn = (cy - mc) * rsqrtf(vc + LN_EPS) * lng + lnb;
      float hy = gact[3 * HH + h] * fast_tanh(cyn);
      hx16[h] = (_Float16)hy;
      hsp[(size_t)(t0 + tl) * (BB * HH)] = (_Float16)hy;
    }
    __syncthreads();                                  // B4
  }
  if (tid < HH) { hxst[b * HH + tid] = hx16[tid]; cxst[b * HH + tid] = cx; }
}

// ---------------- out GEMM: out[b][t][o] = relu(sum_h hs[t][b][h]*Wf[o][h] + bf[o])
__global__ __launch_bounds__(256) void out_gemm(
    const _Float16* __restrict__ hs16, const float* __restrict__ Wf,
    const float* __restrict__ bf, float* __restrict__ out) {
  __shared__ u32 wfl[128][64];    // pairs [kp][o], 32KB
  __shared__ u32 hsl[16][132];    // pairs [p][kp], padded
  const int tid = threadIdx.x;
  const int mbase = blockIdx.x * 16;
#pragma unroll
  for (int i = 0; i < 32; ++i) {  // 8192 pairs of Wf
    int idx = i * 256 + tid;
    int kp = idx >> 6, o = idx & 63;
    wfl[kp][o] = pkf16(Wf[o * HH + kp * 2], Wf[o * HH + kp * 2 + 1]);
  }
#pragma unroll
  for (int i = 0; i < 8; ++i) {   // 2048 pairs of hs
    int idx = i * 256 + tid;
    int p = idx >> 7, kp = idx & 127;
    hsl[p][kp] = *(const u32*)(hs16 + (size_t)(mbase + p) * HH + kp * 2);
  }
  __syncthreads();
  const int o = tid & 63, mi = tid >> 6;
  float bfo = bf[o];
#pragma unroll
  for (int mm = mi; mm < 16; mm += 4) {
    float a0 = bfo, a1 = 0.f, a2 = 0.f, a3 = 0.f;
#pragma unroll
    for (int kp = 0; kp < 128; kp += 4) {
      a0 = fdot2(wfl[kp + 0][o], hsl[mm][kp + 0], a0);
      a1 = fdot2(wfl[kp + 1][o], hsl[mm][kp + 1], a1);
      a2 = fdot2(wfl[kp + 2][o], hsl[mm][kp + 2], a2);
      a3 = fdot2(wfl[kp + 3][o], hsl[mm][kp + 3], a3);
    }
    float r = (a0 + a1) + (a2 + a3);
    int m = mbase + mm;
    out[(size_t)(m & 63) * (T_TOT * OO) + (size_t)(m >> 6) * OO + o] = fmaxf(r, 0.f);
  }
}

extern "C" void kernel_launch(void* const* d_in, const int* in_sizes, int n_in,
                              void* d_out, int out_size, void* d_ws, size_t ws_size,
                              hipStream_t stream) {
  if (n_in < 11) return;
  const float* x    = (const float*)d_in[0];
  const float* Wi   = (const float*)d_in[1];
  const float* bi   = (const float*)d_in[2];
  const float* Wh   = (const float*)d_in[3];
  const float* bh   = (const float*)d_in[4];
  const float* lnag = (const float*)d_in[5];
  const float* lnab = (const float*)d_in[6];
  const float* lng  = (const float*)d_in[7];
  const float* lnb  = (const float*)d_in[8];
  const float* Wf   = (const float*)d_in[9];
  const float* bf   = (const float*)d_in[10];
  float* out = (float*)d_out;

  char* ws = (char*)d_ws;
  uint4* whp4 = (uint4*)ws;                                  // 512 KB
  uint4* wip4 = (uint4*)(ws + (512 << 10));                  // 256 KB
  _Float16* hs16 = (_Float16*)(ws + (1 << 20));              // 32 MB
  _Float16* hxst = (_Float16*)(ws + (1 << 20) + (32 << 20)); // 32 KB
  float* cxst = (float*)(ws + (1 << 20) + (32 << 20) + (64 << 10)); // 64 KB
  const size_t xph_off = (size_t)35 << 20;
  _Float16* xph = (_Float16*)(ws + xph_off);

  size_t avail = ws_size > xph_off ? ws_size - xph_off : 0;
  int ct = T_TOT;
  while (ct > 1 && (size_t)ct * (BB * GG * 2) > avail) ct >>= 1;

  const int scan_smem = 152160;   // 147456 wl + 512 hx + 64 red + 32 red2 + 4096 gact
  (void)hipFuncSetAttribute(reinterpret_cast<const void*>(lstm_scan),
                            hipFuncAttributeMaxDynamicSharedMemorySize, scan_smem);

  prep_wh<<<128, 256, 0, stream>>>(Wh, whp4);
  prep_wi<<<64, 256, 0, stream>>>(Wi, wip4);
  for (int t0 = 0; t0 < T_TOT; t0 += ct) {
    xproj_gemm<<<dim3((ct * BB) / 16, 4), 256, 0, stream>>>(x, wip4, bi, bh, xph, t0 * BB);
    lstm_scan<<<BB, 512, scan_smem, stream>>>(whp4, xph, lnag, lnab, lng, lnb,
                                              hs16, hxst, cxst, t0, ct);
  }
  out_gemm<<<(T_TOT * BB) / 16, 256, 0, stream>>>(hs16, Wf, bf, out);
}